// Round 5
// baseline (180.935 us; speedup 1.0000x reference)
//
#include <hip/hip_runtime.h>
#include <math.h>

// Problem: scores = q[2048x768] @ p[16384x768]^T (fp32 in), per-query
// rank-of-target + log-softmax CE + Gaussian rank weight -> mean (scalar).
// R11 = R10 with two changes, same fp8 math (bit-identical score path):
//  (a) gemm: 1024-thr/256x256/BK=128 -> 512-thr/128x256/BK=64. Regs are
//      128/wave (64 VGPR + 64 acc) = 4 waves/SIMD; LDS 48.5 KB -> TWO
//      independent blocks/CU instead of one monolithic barrier group.
//      R10's 27% MfmaUtil/27% VALU/17% HBM = latency-bound on the
//      vmcnt(0)+barrier drain with nothing co-resident to cover it (m114
//      mechanism). Two decoupled blocks interleave phases and hide it.
//  (b) partials pm/pl/pc chunk-major (idx = chunk*2048 + q): R10's
//      query-major 4B stores caused WRITE_SIZE 59 MB (9x) + ~29 MB
//      write-allocate FETCH. Chunk-major = one 64B line per wave store
//      group, fully dirtied. Finalize adapted (coalesced across q).
// (4th resubmission of R11 — rounds 1-4 hit GPUAcquisitionTimeout.)

#define BQ 2048
#define DD 768
#define NPASS 8
#define PP 16384
#define BM 128
#define BN 256
#define BK 64
#define KITERS 12          // 768/64
#define NBLK 64            // PP/BN
#define MBLK 16            // BQ/BM
#define NCHUNKS 256        // NBLK * 4 n-waves

#define ALPHA_C 2.6f
#define INV_2SIG2 (1.0f/6.48f)   // 1/(2*1.8^2)

typedef __attribute__((ext_vector_type(4))) float floatx4;  // MFMA C/D

// ---------------------------------------------------------------------------
// Kernel 1 (fused): cast q,p -> fp8 e4m3  +  s_t exact-fp32 dots  +  out=0.
// (unchanged from R10)
// ---------------------------------------------------------------------------
#define NQ8   196608     // 2048*768/8
#define NTOT8 1769472    // (2048+16384)*768/8
#define NCB   6912       // NTOT8/256
__global__ __launch_bounds__(256) void prep_kernel(const float* __restrict__ qf,
                                                   const float* __restrict__ pf,
                                                   uint2* __restrict__ qb,
                                                   uint2* __restrict__ pb,
                                                   float* __restrict__ st,
                                                   float* __restrict__ out) {
  const int b = blockIdx.x;
  if (b == 0 && threadIdx.x == 0) *out = 0.f;
  if (b < NCB) {
    const int i = b * 256 + threadIdx.x;        // float8 index
    const float4* src; uint2* dst;
    if (i < NQ8) { src = (const float4*)qf + 2 * (size_t)i; dst = qb + i; }
    else { const size_t j = (size_t)i - NQ8; src = (const float4*)pf + 2 * j; dst = pb + j; }
    const float4 a = src[0], c = src[1];
    unsigned lo = __builtin_amdgcn_cvt_pk_fp8_f32(a.x, a.y, 0, 0);
    lo = __builtin_amdgcn_cvt_pk_fp8_f32(a.z, a.w, lo, 1);
    unsigned hi = __builtin_amdgcn_cvt_pk_fp8_f32(c.x, c.y, 0, 0);
    hi = __builtin_amdgcn_cvt_pk_fp8_f32(c.z, c.w, hi, 1);
    uint2 w; w.x = lo; w.y = hi;
    *dst = w;
  } else {
    const int wv = threadIdx.x >> 6, lane = threadIdx.x & 63;
    const int qi = (b - NCB) * 4 + wv;
    const float4* q4 = (const float4*)(qf + (size_t)qi * DD);
    const float4* p4 = (const float4*)(pf + (size_t)qi * NPASS * DD);
    float acc = 0.f;
#pragma unroll
    for (int u = 0; u < 3; ++u) {   // 192 float4 per row = 64 lanes * 3
      float4 a = q4[lane + 64 * u];
      float4 c = p4[lane + 64 * u];
      acc = fmaf(a.x, c.x, acc);
      acc = fmaf(a.y, c.y, acc);
      acc = fmaf(a.z, c.z, acc);
      acc = fmaf(a.w, c.w, acc);
    }
#pragma unroll
    for (int off = 32; off >= 1; off >>= 1) acc += __shfl_xor(acc, off);
    if (lane == 0) st[qi] = acc;
  }
}

// ---------------------------------------------------------------------------
// Kernel 2: fp8 MFMA GEMM 128x256, BK=64, double-buffered global_load_lds.
// 8 waves (2m x 4n), each wave 4x4 MFMAs of 16x16x32 fp8_fp8 (64x64 out).
// LDS unit = 16 rows x 64 k-bytes = 1 KB; A: unit wv (8 units), B: units
// wv*2+u (16 units). Staged wave-uniform base + lane*16 (global_load_lds).
// Unit layout [kchunk(16B)][row][byte]: a-frag k = ks*32 + lq*8 + j ->
// intra = (ks*2+(lq>>1))*256 + lm*16 + (lq&1)*8 (same mapping as R4-R10;
// K-order across kt,ks identical to R10 -> bit-identical scores).
// C/D: col=lane&15, row=(lane>>4)*4+reg.  2 blocks/CU co-resident.
// ---------------------------------------------------------------------------
__global__ __launch_bounds__(512) void gemm_kernel(const unsigned char* __restrict__ qb,
                                                   const unsigned char* __restrict__ pb,
                                                   const float* __restrict__ st,
                                                   float* __restrict__ pm,
                                                   float* __restrict__ pl,
                                                   float* __restrict__ pc) {
  __shared__ unsigned char As[2][8 * 1024];    // [buf][unit][1 KB]  16 KB
  __shared__ unsigned char Bs[2][16 * 1024];   // [buf][unit][1 KB]  32 KB
  __shared__ float st_lds[BM];

  const int t = threadIdx.x;
  const int lane = t & 63;
  const int wv = t >> 6;            // 0..7
  const int wm = wv >> 2, wn = wv & 3;
  const int bid = blockIdx.x;       // 0..1023
  const int xcd = bid & 7;          // round-robin XCD assignment
  const int nb = xcd * 8 + ((bid >> 3) & 7);   // XCD-private pb slice (1.5 MB)
  const int mb = bid >> 6;          // 0..15
  const int qbase = mb * BM;
  const int n0 = nb * BN;
  const int lm = lane & 15;
  const int lq = lane >> 4;
  const int lds_lane = lane * 16;

  if (t < BM) st_lds[t] = st[qbase + t];

  floatx4 acc[4][4];
#pragma unroll
  for (int i = 0; i < 4; ++i)
#pragma unroll
    for (int j = 0; j < 4; ++j) acc[i][j] = (floatx4){0.f, 0.f, 0.f, 0.f};

  const size_t arow = (size_t)(qbase + wv * 16 + lm) * DD;
  const size_t brow = (size_t)(n0 + wv * 32 + lm) * DD;

  // stage(kt, buf): 3 loads/wave (A unit wv; B units wv*2, wv*2+1), 1 KB each
#define STAGE(KT, BUF)                                                          \
  {                                                                             \
    const size_t koff = (size_t)(KT) * BK + lq * 16;                            \
    __builtin_amdgcn_global_load_lds(                                           \
        (const __attribute__((address_space(1))) void*)(qb + arow + koff),      \
        (__attribute__((address_space(3))) void*)(&As[BUF][wv * 1024] + lds_lane), \
        16, 0, 0);                                                              \
    _Pragma("unroll")                                                           \
    for (int u = 0; u < 2; ++u) {                                               \
      __builtin_amdgcn_global_load_lds(                                         \
          (const __attribute__((address_space(1))) void*)(pb + brow + (size_t)u * 16 * DD + koff), \
          (__attribute__((address_space(3))) void*)(&Bs[BUF][(wv * 2 + u) * 1024] + lds_lane), \
          16, 0, 0);                                                            \
    }                                                                           \
  }

  STAGE(0, 0)
  for (int kt = 0; kt < KITERS; ++kt) {
    const int cb = kt & 1;
    __syncthreads();                 // drains vmcnt -> buf cb ready
    if (kt < KITERS - 1) STAGE(kt + 1, cb ^ 1)   // flies under compute below
#pragma unroll
    for (int ks = 0; ks < 2; ++ks) {
      const int intra = (ks * 2 + (lq >> 1)) * 256 + lm * 16 + (lq & 1) * 8;
      long a[4], b[4];
#pragma unroll
      for (int i = 0; i < 4; ++i)
        a[i] = *(const long*)(&As[cb][(wm * 4 + i) * 1024] + intra);
#pragma unroll
      for (int j = 0; j < 4; ++j)
        b[j] = *(const long*)(&Bs[cb][(wn * 4 + j) * 1024] + intra);
#pragma unroll
      for (int i = 0; i < 4; ++i)
#pragma unroll
        for (int j = 0; j < 4; ++j)
          acc[i][j] = __builtin_amdgcn_mfma_f32_16x16x32_fp8_fp8(a[i], b[j], acc[i][j], 0, 0, 0);
    }
  }

  // ---- fused epilogue: per-row (query) max / sumexp / count over 64 cols ----
  // Chunk-major partials: lanes lm==0 (lq=0..3) x r=0..3 cover 16 consecutive
  // queries -> one 64B line per (wave,i), fully dirtied within the r loop.
  const int chunk = nb * 4 + wn;
  float* const pmc = pm + (size_t)chunk * BQ;
  float* const plc = pl + (size_t)chunk * BQ;
  float* const pcc = pc + (size_t)chunk * BQ;
#pragma unroll
  for (int i = 0; i < 4; ++i) {
#pragma unroll
    for (int r = 0; r < 4; ++r) {
      const int rl = wm * 64 + i * 16 + lq * 4 + r;   // local query row
      float mx = fmaxf(fmaxf(acc[i][0][r], acc[i][1][r]),
                       fmaxf(acc[i][2][r], acc[i][3][r]));
#pragma unroll
      for (int off = 1; off <= 8; off <<= 1) mx = fmaxf(mx, __shfl_xor(mx, off));
      const float stv = st_lds[rl];
      const int qg = qbase + rl;
      const int tcol = qg * NPASS;
      float sum = 0.f, c = 0.f;
#pragma unroll
      for (int j = 0; j < 4; ++j) {
        const float s = acc[i][j][r];
        sum += __expf(s - mx);
        const int cg = n0 + wn * 64 + j * 16 + lm;
        if (s > stv && cg != tcol) c += 1.f;
      }
#pragma unroll
      for (int off = 1; off <= 8; off <<= 1) {
        sum += __shfl_xor(sum, off);
        c += __shfl_xor(c, off);
      }
      if (lm == 0) {
        pmc[qg] = mx; plc[qg] = sum; pcc[qg] = c;
      }
    }
  }
}

// ---------------------------------------------------------------------------
// Kernel 3: merge 256 chunks/query (chunk-major partials), weighted CE, mean.
// 32 blocks x 256 thr; block owns 64 queries; wave wv owns chunks wv*64..+63.
// Loads coalesced across q (lane = q within block). Online max-merge.
// ---------------------------------------------------------------------------
__global__ __launch_bounds__(256) void finalize_kernel(const float* __restrict__ st,
                                                       const float* __restrict__ pm,
                                                       const float* __restrict__ pl,
                                                       const float* __restrict__ pc,
                                                       float* __restrict__ out) {
  const int wv = threadIdx.x >> 6, lane = threadIdx.x & 63;
  const int q = blockIdx.x * 64 + lane;
  const int c0 = wv * 64;
  float m = -1e30f, l = 0.f, c = 0.f;
#pragma unroll 4
  for (int ch = 0; ch < 64; ++ch) {
    const size_t idx = (size_t)(c0 + ch) * BQ + q;
    const float mv = pm[idx], lv = pl[idx], cv = pc[idx];
    const float nm = fmaxf(m, mv);
    l = l * __expf(m - nm) + lv * __expf(mv - nm);
    m = nm; c += cv;
  }
  __shared__ float sm[4][64], sl[4][64], sc[4][64];
  sm[wv][lane] = m; sl[wv][lane] = l; sc[wv][lane] = c;
  __syncthreads();
  if (wv == 0) {
    float M = sm[0][lane], L = sl[0][lane], C = sc[0][lane];
#pragma unroll
    for (int w = 1; w < 4; ++w) {
      const float mv = sm[w][lane];
      const float nm = fmaxf(M, mv);
      L = L * __expf(M - nm) + sl[w][lane] * __expf(mv - nm);
      M = nm; C += sc[w][lane];
    }
    const float raw = logf(L) + M - st[q];     // -log_softmax[target]
    const float dr = C - 1.0f;                 // rank - OPTIMAL_RANK
    const float w = 1.0f + ALPHA_C * __expf(-(dr * dr) * INV_2SIG2);
    float loss = raw * w * (1.0f / (float)BQ);
#pragma unroll
    for (int off = 32; off >= 1; off >>= 1) loss += __shfl_xor(loss, off);
    if (lane == 0) atomicAdd(out, loss);
  }
}

// ---------------------------------------------------------------------------
extern "C" void kernel_launch(void* const* d_in, const int* in_sizes, int n_in,
                              void* d_out, int out_size, void* d_ws, size_t ws_size,
                              hipStream_t stream) {
  const float* q = (const float*)d_in[0];
  const float* p = (const float*)d_in[1];
  char* ws = (char*)d_ws;
  unsigned char* qb = (unsigned char*)ws;                  // 1,572,864 B
  unsigned char* pb = (unsigned char*)(ws + 1572864);      // 12,582,912 B
  float* st = (float*)(ws + 14155776);                     // 8 KB
  float* pm = (float*)(ws + 14163968);                     // 2 MB
  float* pl = (float*)(ws + 16261120);                     // 2 MB
  float* pc = (float*)(ws + 18358272);                     // 2 MB (end ~20.5 MB)
  float* out = (float*)d_out;

  prep_kernel<<<NCB + BQ / 4, 256, 0, stream>>>(q, p, (uint2*)qb, (uint2*)pb, st, out);
  gemm_kernel<<<NBLK * MBLK, 512, 0, stream>>>(qb, pb, st, pm, pl, pc);
  finalize_kernel<<<BQ / 64, 256, 0, stream>>>(st, pm, pl, pc, out);
}

// Round 7
// 152.894 us; speedup vs baseline: 1.1834x; 1.1834x over previous
//
#include <hip/hip_runtime.h>
#include <math.h>

// Problem: scores = q[2048x768] @ p[16384x768]^T (fp32 in), per-query
// rank-of-target + log-softmax CE + Gaussian rank weight -> mean (scalar).
// R12: counted-vmcnt pipeline (T4). R11 post-mortem: chunk-major partials
// WORKED (WRITE 59->6 MB, FETCH 43->12.4 MB, HBM 2%) -> kept. The 128x256
// 2-blocks/CU theory FAILED (gemm 72.5->106 us, occupancy 39->22.5%):
// doubling the barrier count doubled the vmcnt(0)+s_barrier drain cost —
// the m97-ceiling mechanism. Fix the drain itself:
//  - 256x256 tile, 16 waves (R10 geometry), BK=64, KITERS=12.
//  - LDS TRIPLE buffer (3 x (16KB A + 16KB B) = 96KB, 1 block/CU).
//  - One raw s_barrier per iter; inline-asm s_waitcnt vmcnt(2) — each wave
//    waits only its OWN stage-t loads (2 in flight x 2 loads); barrier
//    makes it collective. STAGE(t+2) issued AFTER the barrier so the
//    buffer it overwrites (last read iter t-1) is provably free.
//    vmcnt hits 0 only in the peeled final iteration.
//  - K order kt*64+ks*32+lq*8+j identical to R10/R11 -> bit-identical
//    scores, absmax 0.5 expected.
// (Resubmission — round 6 hit GPUAcquisitionTimeout; R12 never ran.)

#define BQ 2048
#define DD 768
#define NPASS 8
#define PP 16384
#define BM 256
#define BN 256
#define BK 64
#define KITERS 12          // 768/64
#define NBLK 64            // PP/BN
#define MBLK 8             // BQ/BM
#define NCHUNKS 256        // NBLK * 4 n-waves

#define ALPHA_C 2.6f
#define INV_2SIG2 (1.0f/6.48f)   // 1/(2*1.8^2)

typedef __attribute__((ext_vector_type(4))) float floatx4;  // MFMA C/D

// ---------------------------------------------------------------------------
// Kernel 1 (fused): cast q,p -> fp8 e4m3  +  s_t exact-fp32 dots  +  out=0.
// (unchanged)
// ---------------------------------------------------------------------------
#define NQ8   196608     // 2048*768/8
#define NTOT8 1769472    // (2048+16384)*768/8
#define NCB   6912       // NTOT8/256
__global__ __launch_bounds__(256) void prep_kernel(const float* __restrict__ qf,
                                                   const float* __restrict__ pf,
                                                   uint2* __restrict__ qb,
                                                   uint2* __restrict__ pb,
                                                   float* __restrict__ st,
                                                   float* __restrict__ out) {
  const int b = blockIdx.x;
  if (b == 0 && threadIdx.x == 0) *out = 0.f;
  if (b < NCB) {
    const int i = b * 256 + threadIdx.x;        // float8 index
    const float4* src; uint2* dst;
    if (i < NQ8) { src = (const float4*)qf + 2 * (size_t)i; dst = qb + i; }
    else { const size_t j = (size_t)i - NQ8; src = (const float4*)pf + 2 * j; dst = pb + j; }
    const float4 a = src[0], c = src[1];
    unsigned lo = __builtin_amdgcn_cvt_pk_fp8_f32(a.x, a.y, 0, 0);
    lo = __builtin_amdgcn_cvt_pk_fp8_f32(a.z, a.w, lo, 1);
    unsigned hi = __builtin_amdgcn_cvt_pk_fp8_f32(c.x, c.y, 0, 0);
    hi = __builtin_amdgcn_cvt_pk_fp8_f32(c.z, c.w, hi, 1);
    uint2 w; w.x = lo; w.y = hi;
    *dst = w;
  } else {
    const int wv = threadIdx.x >> 6, lane = threadIdx.x & 63;
    const int qi = (b - NCB) * 4 + wv;
    const float4* q4 = (const float4*)(qf + (size_t)qi * DD);
    const float4* p4 = (const float4*)(pf + (size_t)qi * NPASS * DD);
    float acc = 0.f;
#pragma unroll
    for (int u = 0; u < 3; ++u) {   // 192 float4 per row = 64 lanes * 3
      float4 a = q4[lane + 64 * u];
      float4 c = p4[lane + 64 * u];
      acc = fmaf(a.x, c.x, acc);
      acc = fmaf(a.y, c.y, acc);
      acc = fmaf(a.z, c.z, acc);
      acc = fmaf(a.w, c.w, acc);
    }
#pragma unroll
    for (int off = 32; off >= 1; off >>= 1) acc += __shfl_xor(acc, off);
    if (lane == 0) st[qi] = acc;
  }
}

// ---------------------------------------------------------------------------
// Kernel 2: fp8 MFMA GEMM 256x256, BK=64, TRIPLE-buffered global_load_lds
// with counted vmcnt. 16 waves (4m x 4n), each wave 4x4 MFMAs of 16x16x32
// fp8_fp8 (64x64 out). LDS unit = 16 rows x 64 k-bytes = 1 KB; A tile = 16
// units (one per wave), B tile = 16 units. Staged wave-uniform base +
// lane*16 (global_load_lds semantics). Unit layout [kchunk 16B][row][byte]:
// a-frag k = ks*32 + lq*8 + j -> intra = (ks*2+(lq>>1))*256+lm*16+(lq&1)*8
// (proven mapping R4-R11). C/D: col=lane&15, row=(lane>>4)*4+reg.
// Pipeline per iter t: [vmcnt(2): own stage-t done] [s_barrier: all done,
// and all waves past iter t-1 reads] [STAGE(t+2) into buf (t+2)%3 — the
// buffer last read at t-1, provably free] [compute buf t%3].
// ---------------------------------------------------------------------------
__global__ __launch_bounds__(1024) void gemm_kernel(const unsigned char* __restrict__ qb,
                                                    const unsigned char* __restrict__ pb,
                                                    const float* __restrict__ st,
                                                    float* __restrict__ pm,
                                                    float* __restrict__ pl,
                                                    float* __restrict__ pc) {
  __shared__ unsigned char As[3][16 * 1024];   // 48 KB
  __shared__ unsigned char Bs[3][16 * 1024];   // 48 KB
  __shared__ float st_lds[BM];

  const int t = threadIdx.x;
  const int lane = t & 63;
  const int wv = t >> 6;            // 0..15
  const int wm = wv >> 2, wn = wv & 3;
  const int bid = blockIdx.x;       // 0..511
  const int xcd = bid & 7;          // round-robin XCD assignment
  const int nb = xcd * 8 + ((bid >> 3) & 7);   // XCD-private pb slice (1.5 MB)
  const int mb = bid >> 6;          // 0..7
  const int qbase = mb * BM;
  const int n0 = nb * BN;
  const int lm = lane & 15;
  const int lq = lane >> 4;
  const int lds_lane = lane * 16;

  // st staging FIRST: its load's vmcnt is drained by the compiler before the
  // dependent ds_write, before any pipeline stages are issued.
  if (t < BM) st_lds[t] = st[qbase + t];

  floatx4 acc[4][4];
#pragma unroll
  for (int i = 0; i < 4; ++i)
#pragma unroll
    for (int j = 0; j < 4; ++j) acc[i][j] = (floatx4){0.f, 0.f, 0.f, 0.f};

  const size_t arow = (size_t)(qbase + wv * 16 + lm) * DD;
  const size_t brow = (size_t)(n0 + wv * 16 + lm) * DD;

  // stage(kt, buf): 2 loads/wave (A unit wv, B unit wv), 1 KB each.
#define STAGE(KT, BUF)                                                          \
  {                                                                             \
    const size_t koff = (size_t)(KT) * BK + lq * 16;                            \
    __builtin_amdgcn_global_load_lds(                                           \
        (const __attribute__((address_space(1))) void*)(qb + arow + koff),      \
        (__attribute__((address_space(3))) void*)(&As[BUF][wv * 1024] + lds_lane), \
        16, 0, 0);                                                              \
    __builtin_amdgcn_global_load_lds(                                           \
        (const __attribute__((address_space(1))) void*)(pb + brow + koff),      \
        (__attribute__((address_space(3))) void*)(&Bs[BUF][wv * 1024] + lds_lane), \
        16, 0, 0);                                                              \
  }

#define COMPUTE(CB)                                                             \
  _Pragma("unroll")                                                             \
  for (int ks = 0; ks < 2; ++ks) {                                              \
    const int intra = (ks * 2 + (lq >> 1)) * 256 + lm * 16 + (lq & 1) * 8;      \
    long a[4], b[4];                                                            \
    _Pragma("unroll")                                                           \
    for (int i = 0; i < 4; ++i)                                                 \
      a[i] = *(const long*)(&As[CB][(wm * 4 + i) * 1024] + intra);              \
    _Pragma("unroll")                                                           \
    for (int j = 0; j < 4; ++j)                                                 \
      b[j] = *(const long*)(&Bs[CB][(wn * 4 + j) * 1024] + intra);              \
    _Pragma("unroll")                                                           \
    for (int i = 0; i < 4; ++i)                                                 \
      _Pragma("unroll")                                                         \
      for (int j = 0; j < 4; ++j)                                               \
        acc[i][j] = __builtin_amdgcn_mfma_f32_16x16x32_fp8_fp8(a[i], b[j], acc[i][j], 0, 0, 0); \
  }

  STAGE(0, 0)
  STAGE(1, 1)
  int cur = 0;            // buffer holding K-tile kt
  int stg = 2;            // buffer to stage K-tile kt+2 into
  for (int kt = 0; kt < KITERS - 1; ++kt) {
    // own stage-kt loads done (2 newest = stage kt+1 may remain in flight)
    asm volatile("s_waitcnt vmcnt(2)" ::: "memory");
    __builtin_amdgcn_s_barrier();          // all waves: stage kt complete,
    __builtin_amdgcn_sched_barrier(0);     // and all past iter kt-1 reads
    if (kt < KITERS - 2) STAGE(kt + 2, stg)
    COMPUTE(cur)
    cur = (cur == 2) ? 0 : cur + 1;
    stg = (stg == 2) ? 0 : stg + 1;
  }
  // peeled final iteration: drain the last stage
  asm volatile("s_waitcnt vmcnt(0)" ::: "memory");
  __builtin_amdgcn_s_barrier();
  __builtin_amdgcn_sched_barrier(0);
  COMPUTE(cur)

  // ---- fused epilogue: per-row (query) max / sumexp / count over 64 cols ----
  // Chunk-major partials: lanes lm==0 (lq=0..3) x r=0..3 cover 16 consecutive
  // queries -> one 64B line per (wave,i), fully dirtied within the r loop.
  const int chunk = nb * 4 + wn;
  float* const pmc = pm + (size_t)chunk * BQ;
  float* const plc = pl + (size_t)chunk * BQ;
  float* const pcc = pc + (size_t)chunk * BQ;
#pragma unroll
  for (int i = 0; i < 4; ++i) {
#pragma unroll
    for (int r = 0; r < 4; ++r) {
      const int rl = wm * 64 + i * 16 + lq * 4 + r;   // local query row
      float mx = fmaxf(fmaxf(acc[i][0][r], acc[i][1][r]),
                       fmaxf(acc[i][2][r], acc[i][3][r]));
#pragma unroll
      for (int off = 1; off <= 8; off <<= 1) mx = fmaxf(mx, __shfl_xor(mx, off));
      const float stv = st_lds[rl];
      const int qg = qbase + rl;
      const int tcol = qg * NPASS;
      float sum = 0.f, c = 0.f;
#pragma unroll
      for (int j = 0; j < 4; ++j) {
        const float s = acc[i][j][r];
        sum += __expf(s - mx);
        const int cg = n0 + wn * 64 + j * 16 + lm;
        if (s > stv && cg != tcol) c += 1.f;
      }
#pragma unroll
      for (int off = 1; off <= 8; off <<= 1) {
        sum += __shfl_xor(sum, off);
        c += __shfl_xor(c, off);
      }
      if (lm == 0) {
        pmc[qg] = mx; plc[qg] = sum; pcc[qg] = c;
      }
    }
  }
}

// ---------------------------------------------------------------------------
// Kernel 3: merge 256 chunks/query (chunk-major partials), weighted CE, mean.
// 32 blocks x 256 thr; block owns 64 queries; wave wv owns chunks wv*64..+63.
// Loads coalesced across q (lane = q within block). Online max-merge.
// ---------------------------------------------------------------------------
__global__ __launch_bounds__(256) void finalize_kernel(const float* __restrict__ st,
                                                       const float* __restrict__ pm,
                                                       const float* __restrict__ pl,
                                                       const float* __restrict__ pc,
                                                       float* __restrict__ out) {
  const int wv = threadIdx.x >> 6, lane = threadIdx.x & 63;
  const int q = blockIdx.x * 64 + lane;
  const int c0 = wv * 64;
  float m = -1e30f, l = 0.f, c = 0.f;
#pragma unroll 4
  for (int ch = 0; ch < 64; ++ch) {
    const size_t idx = (size_t)(c0 + ch) * BQ + q;
    const float mv = pm[idx], lv = pl[idx], cv = pc[idx];
    const float nm = fmaxf(m, mv);
    l = l * __expf(m - nm) + lv * __expf(mv - nm);
    m = nm; c += cv;
  }
  __shared__ float sm[4][64], sl[4][64], sc[4][64];
  sm[wv][lane] = m; sl[wv][lane] = l; sc[wv][lane] = c;
  __syncthreads();
  if (wv == 0) {
    float M = sm[0][lane], L = sl[0][lane], C = sc[0][lane];
#pragma unroll
    for (int w = 1; w < 4; ++w) {
      const float mv = sm[w][lane];
      const float nm = fmaxf(M, mv);
      L = L * __expf(M - nm) + sl[w][lane] * __expf(mv - nm);
      M = nm; C += sc[w][lane];
    }
    const float raw = logf(L) + M - st[q];     // -log_softmax[target]
    const float dr = C - 1.0f;                 // rank - OPTIMAL_RANK
    const float w = 1.0f + ALPHA_C * __expf(-(dr * dr) * INV_2SIG2);
    float loss = raw * w * (1.0f / (float)BQ);
#pragma unroll
    for (int off = 32; off >= 1; off >>= 1) loss += __shfl_xor(loss, off);
    if (lane == 0) atomicAdd(out, loss);
  }
}

// ---------------------------------------------------------------------------
extern "C" void kernel_launch(void* const* d_in, const int* in_sizes, int n_in,
                              void* d_out, int out_size, void* d_ws, size_t ws_size,
                              hipStream_t stream) {
  const float* q = (const float*)d_in[0];
  const float* p = (const float*)d_in[1];
  char* ws = (char*)d_ws;
  unsigned char* qb = (unsigned char*)ws;                  // 1,572,864 B
  unsigned char* pb = (unsigned char*)(ws + 1572864);      // 12,582,912 B
  float* st = (float*)(ws + 14155776);                     // 8 KB
  float* pm = (float*)(ws + 14163968);                     // 2 MB
  float* pl = (float*)(ws + 16261120);                     // 2 MB
  float* pc = (float*)(ws + 18358272);                     // 2 MB (end ~20.5 MB)
  float* out = (float*)d_out;

  prep_kernel<<<NCB + BQ / 4, 256, 0, stream>>>(q, p, (uint2*)qb, (uint2*)pb, st, out);
  gemm_kernel<<<NBLK * MBLK, 1024, 0, stream>>>(qb, pb, st, pm, pl, pc);
  finalize_kernel<<<BQ / 64, 256, 0, stream>>>(st, pm, pl, pc, out);
}